// Round 2
// baseline (576.117 us; speedup 1.0000x reference)
//
#include <hip/hip_runtime.h>
#include <hip/hip_cooperative_groups.h>
#include <math.h>

namespace cg = cooperative_groups;

// ---------------------------------------------------------------------------
// QuantumGenerator, fused persistent version.
// Facts used:
//  * per channel only V = U[0:4,0:4] of the 8x8 unitary matters
//    (psi0[4:8]==0 and only probs[:4] kept)
//  * every layer is layout-preserving on the per-batch 4096-float flat vector
//  * BN channel of a layer's output == (input channel >> 2)
// One workgroup owns one batch (4096 floats in LDS) across all 4 layers;
// grid.sync() at each BN boundary; BN sums via 8-way-banked global atomics.
// ---------------------------------------------------------------------------

// ---- build the 340 4x4 V blocks + zero the stats accumulators (1360 f) ----
__global__ __launch_bounds__(256) void build_V_kernel(
    const float* __restrict__ w1, const float* __restrict__ w2,
    const float* __restrict__ w3, const float* __restrict__ w4,
    float* __restrict__ V, float* __restrict__ acc)
{
    int t = blockIdx.x * blockDim.x + threadIdx.x;
    int j = t - 512;
    if (j >= 0 && j < 1360) acc[j] = 0.0f;   // zero banked BN accumulators
    if (t >= 340) return;
    const float* w; float* vout;
    if (t < 256)      { w = w1 + t*18;        vout = V + t*16; }
    else if (t < 320) { w = w2 + (t-256)*18;  vout = V + 4096 + (t-256)*16; }
    else if (t < 336) { w = w3 + (t-320)*18;  vout = V + 5120 + (t-320)*16; }
    else              { w = w4 + (t-336)*18;  vout = V + 5376 + (t-336)*16; }
    const int perm[8] = {0,5,7,2,3,6,4,1};   // CNOT ring row permutation
    float U[8][8];
    #pragma unroll
    for (int i=0;i<8;i++)
        #pragma unroll
        for (int jj=0;jj<8;jj++) U[i][jj] = (i==jj) ? 1.0f : 0.0f;
    for (int l=0;l<6;l++){
        float c0 = cosf(0.5f*w[l*3+0]), s0 = sinf(0.5f*w[l*3+0]);
        float c1 = cosf(0.5f*w[l*3+1]), s1 = sinf(0.5f*w[l*3+1]);
        float c2 = cosf(0.5f*w[l*3+2]), s2 = sinf(0.5f*w[l*3+2]);
        #pragma unroll
        for (int col=0; col<8; col++){
            float v[8];
            #pragma unroll
            for (int r=0;r<8;r++) v[r] = U[r][col];
            #pragma unroll
            for (int bb=0;bb<8;bb+=2){ float x=v[bb], y=v[bb+1]; v[bb]=c2*x-s2*y; v[bb+1]=s2*x+c2*y; }
            #pragma unroll
            for (int g=0;g<8;g+=4)
                #pragma unroll
                for (int i=0;i<2;i++){ int a=g+i, bq=g+i+2; float x=v[a], y=v[bq]; v[a]=c1*x-s1*y; v[bq]=s1*x+c1*y; }
            #pragma unroll
            for (int i=0;i<4;i++){ float x=v[i], y=v[i+4]; v[i]=c0*x-s0*y; v[i+4]=s0*x+c0*y; }
            #pragma unroll
            for (int r=0;r<8;r++) U[perm[r]][col] = v[r];
        }
    }
    #pragma unroll
    for (int jj=0;jj<4;jj++)
        #pragma unroll
        for (int k=0;k<4;k++) vout[jj*4+k] = U[jj][k];
}

// ---- one qcnn layer, in-place on the wg's LDS batch ------------------------
template<int C, int H, int W, bool BN>
__device__ __forceinline__ void layer_step(
    float* __restrict__ data, const float* __restrict__ Vg,
    const float* __restrict__ sSc, const float* __restrict__ sSh,
    float* __restrict__ sbin, float* __restrict__ accL, int bank,
    float* __restrict__ gout, int b)
{
    constexpr int HW  = H*W;
    constexpr int P   = HW/4;
    constexpr int OW  = W/2;
    constexpr int OC  = C/4;                 // BN channels of the OUTPUT
    constexpr int LP  = (P==4)?2:(P==16)?4:(P==64)?6:8;
    constexpr int LOW = (OW==2)?1:(OW==4)?2:(OW==8)?3:4;
    constexpr int RED = ((1<<(LP+2)) < 64) ? (1<<(LP+2)) : 64; // lanes per oc
    const int tid = threadIdx.x;

    if (tid < 2*OC) sbin[tid] = 0.0f;
    __syncthreads();                         // also covers prior LDS writes

    // read phase: 4 units/thread, all inputs into registers (in-place safe)
    float xv[4][4];
    #pragma unroll
    for (int k=0;k<4;k++){
        int u = tid + 256*k;
        int c = u >> LP, p = u & (P-1);
        int oh = p >> LOW, ow = p & (OW-1);
        int base = c*HW + (oh*2)*W + (ow*2);
        float x0 = data[base], x1 = data[base+1];
        float x2 = data[base+W], x3 = data[base+W+1];
        if constexpr (BN){
            float sc = sSc[c], sh = sSh[c];
            x0 = fmaxf(fmaf(x0,sc,sh), 0.0f);
            x1 = fmaxf(fmaf(x1,sc,sh), 0.0f);
            x2 = fmaxf(fmaf(x2,sc,sh), 0.0f);
            x3 = fmaxf(fmaf(x3,sc,sh), 0.0f);
        }
        xv[k][0]=x0; xv[k][1]=x1; xv[k][2]=x2; xv[k][3]=x3;
    }
    __syncthreads();

    // compute + write-back + stats
    #pragma unroll
    for (int k=0;k<4;k++){
        int u = tid + 256*k;
        int c = u >> LP, p = u & (P-1);
        float x0=xv[k][0], x1=xv[k][1], x2=xv[k][2], x3=xv[k][3];
        float nrm = sqrtf(x0*x0 + x1*x1 + x2*x2 + x3*x3);
        float inv = 1.0f / fmaxf(nrm, 1e-9f);
        float a0=x0*inv, a1=x1*inv, a2=x2*inv, a3=x3*inv;
        const float4* Vc = reinterpret_cast<const float4*>(Vg + (c<<4));
        float4 v0 = Vc[0], v1 = Vc[1], v2 = Vc[2], v3 = Vc[3];
        float q0 = v0.x*a0 + v0.y*a1 + v0.z*a2 + v0.w*a3;
        float q1 = v1.x*a0 + v1.y*a1 + v1.z*a2 + v1.w*a3;
        float q2 = v2.x*a0 + v2.y*a1 + v2.z*a2 + v2.w*a3;
        float q3 = v3.x*a0 + v3.y*a1 + v3.z*a2 + v3.w*a3;
        q0*=q0; q1*=q1; q2*=q2; q3*=q3;
        float dinv = 1.0f / fmaxf(q0+q1+q2+q3, 1e-9f);
        float d0=q0*dinv, d1=q1*dinv, d2=q2*dinv, d3=q3*dinv;
        float4 o4 = make_float4(d0,d1,d2,d3);
        reinterpret_cast<float4*>(data)[c*P + p] = o4;     // u == c*P+p
        if (gout)
            reinterpret_cast<float4*>(gout)[(size_t)b*1024 + u] = o4;
        float ls  = d0+d1+d2+d3;
        float lss = d0*d0 + d1*d1 + d2*d2 + d3*d3;
        #pragma unroll
        for (int off=1; off<RED; off<<=1){
            ls  += __shfl_xor(ls,  off);
            lss += __shfl_xor(lss, off);
        }
        if ((tid & (RED-1)) == 0){
            int oc = u >> (LP+2);
            atomicAdd(&sbin[oc],      ls);
            atomicAdd(&sbin[OC + oc], lss);
        }
    }
    __syncthreads();

    // one global atomic per (wg, channel), banked 8 ways
    if (tid < OC){
        atomicAdd(&accL[bank*2*OC + tid],      sbin[tid]);
        atomicAdd(&accL[bank*2*OC + OC + tid], sbin[OC + tid]);
    }
}

template<int OC>
__device__ __forceinline__ void bn_params(
    const float* __restrict__ accL,
    const float* __restrict__ gamma, const float* __restrict__ beta,
    float invN, float* __restrict__ sSc, float* __restrict__ sSh, int tid)
{
    if (tid < OC){
        float s=0.0f, q=0.0f;
        #pragma unroll
        for (int bk=0;bk<8;bk++){
            s += accL[bk*2*OC + tid];
            q += accL[bk*2*OC + OC + tid];
        }
        float mean = s*invN;
        float var  = q*invN - mean*mean;
        float r    = 1.0f / sqrtf(var + 1e-5f);
        float sc   = gamma[tid]*r;
        sSc[tid] = sc;
        sSh[tid] = beta[tid] - mean*sc;
    }
    __syncthreads();
}

__global__ __launch_bounds__(256, 4) void fused_kernel(
    const float* __restrict__ z, const float* __restrict__ V,
    float* __restrict__ acc,
    const float* __restrict__ g2, const float* __restrict__ b2,
    const float* __restrict__ g3, const float* __restrict__ b3,
    const float* __restrict__ g4, const float* __restrict__ b4,
    const float* __restrict__ gf, const float* __restrict__ bf,
    float* __restrict__ out_tanh, float* __restrict__ out_s4,
    float* __restrict__ out_bn)
{
    __shared__ __align__(16) float data[4096];
    __shared__ float sbin[128];
    __shared__ float sSc[64], sSh[64];
    const int tid  = threadIdx.x;
    const int b    = blockIdx.x;
    const int bank = b & 7;
    cg::grid_group grid = cg::this_grid();

    float* acc1 = acc;          // 8*128
    float* acc2 = acc + 1024;   // 8*32
    float* acc3 = acc + 1280;   // 8*8
    float* acc4 = acc + 1344;   // 8*2

    // load the batch into LDS (coalesced float4)
    const float4* zb = reinterpret_cast<const float4*>(z) + (size_t)b*1024;
    float4* dv = reinterpret_cast<float4*>(data);
    #pragma unroll
    for (int k=0;k<4;k++) dv[k*256+tid] = zb[k*256+tid];
    // layer_step's leading __syncthreads covers the load->read hazard

    layer_step<256,4,4,false>(data, V,      nullptr, nullptr, sbin, acc1, bank, nullptr, b);
    grid.sync();
    bn_params<64>(acc1, g2, b2, 1.0f/65536.0f,   sSc, sSh, tid);

    layer_step<64,8,8,true>(data, V+4096, sSc, sSh, sbin, acc2, bank, nullptr, b);
    grid.sync();
    bn_params<16>(acc2, g3, b3, 1.0f/262144.0f,  sSc, sSh, tid);

    layer_step<16,16,16,true>(data, V+5120, sSc, sSh, sbin, acc3, bank, nullptr, b);
    grid.sync();
    bn_params<4>(acc3, g4, b4, 1.0f/1048576.0f,  sSc, sSh, tid);

    layer_step<4,32,32,true>(data, V+5376, sSc, sSh, sbin, acc4, bank, out_s4, b);
    grid.sync();

    // final BN (single channel) + tanh, straight from LDS
    float s=0.0f, q=0.0f;
    #pragma unroll
    for (int bk=0;bk<8;bk++){ s += acc4[bk*2]; q += acc4[bk*2+1]; }
    float mean = s*(1.0f/4194304.0f);
    float var  = q*(1.0f/4194304.0f) - mean*mean;
    float r    = 1.0f / sqrtf(var + 1e-5f);
    float sc   = gf[0]*r;
    float sh   = bf[0] - mean*sc;
    float4* ot = reinterpret_cast<float4*>(out_tanh) + (size_t)b*1024;
    float4* ob = reinterpret_cast<float4*>(out_bn)   + (size_t)b*1024;
    #pragma unroll
    for (int k=0;k<4;k++){
        float4 v = dv[k*256+tid];
        float4 bnv = make_float4(fmaf(v.x,sc,sh), fmaf(v.y,sc,sh),
                                 fmaf(v.z,sc,sh), fmaf(v.w,sc,sh));
        ob[k*256+tid] = bnv;
        ot[k*256+tid] = make_float4(tanhf(bnv.x), tanhf(bnv.y),
                                    tanhf(bnv.z), tanhf(bnv.w));
    }
}

extern "C" void kernel_launch(void* const* d_in, const int* in_sizes, int n_in,
                              void* d_out, int out_size, void* d_ws, size_t ws_size,
                              hipStream_t stream)
{
    const float* z      = (const float*)d_in[0];
    const float* w1     = (const float*)d_in[1];
    const float* w2     = (const float*)d_in[2];
    const float* w3     = (const float*)d_in[3];
    const float* w4     = (const float*)d_in[4];
    const float* gamma2 = (const float*)d_in[5];
    const float* beta2  = (const float*)d_in[6];
    const float* gamma3 = (const float*)d_in[7];
    const float* beta3  = (const float*)d_in[8];
    const float* gamma4 = (const float*)d_in[9];
    const float* beta4  = (const float*)d_in[10];
    const float* gammaf = (const float*)d_in[11];
    const float* betaf  = (const float*)d_in[12];
    float* out = (float*)d_out;
    float* ws  = (float*)d_ws;

    float* V   = ws;          // 5440 floats
    float* acc = ws + 8192;   // 1360 floats (8-way banked BN accumulators)

    float* out_tanh = out;               // output 0
    float* out_s4   = out + 4194304;     // output 1
    float* out_bn   = out + 8388608;     // output 2

    build_V_kernel<<<8, 256, 0, stream>>>(w1, w2, w3, w4, V, acc);

    void* args[] = {
        (void*)&z, (void*)&V, (void*)&acc,
        (void*)&gamma2, (void*)&beta2,
        (void*)&gamma3, (void*)&beta3,
        (void*)&gamma4, (void*)&beta4,
        (void*)&gammaf, (void*)&betaf,
        (void*)&out_tanh, (void*)&out_s4, (void*)&out_bn
    };
    hipLaunchCooperativeKernel((const void*)fused_kernel,
                               dim3(1024), dim3(256), args, 0, stream);
}

// Round 3
// 175.973 us; speedup vs baseline: 3.2739x; 3.2739x over previous
//
#include <hip/hip_runtime.h>
#include <math.h>

// ---------------------------------------------------------------------------
// QuantumGenerator, 6-launch version (grid.sync measured at ~115us/sync on
// gfx950 -> kernel boundaries are the global barrier instead).
// Facts used:
//  * per channel only V = U[0:4,0:4] of the 8x8 unitary matters
//  * every layer is layout-preserving on the per-batch 4096-float flat vector
//  * BN channel of a layer's output == (input channel >> 2)
// BN stats: blocks atomicAdd per-channel partials into 8-way-banked global
// accumulators; the CONSUMER kernel folds them into scale/shift per block.
// ---------------------------------------------------------------------------

#define NB 1024

// ---- build the 340 4x4 V blocks + zero the stats accumulators (1360 f) ----
__global__ __launch_bounds__(256) void build_V_kernel(
    const float* __restrict__ w1, const float* __restrict__ w2,
    const float* __restrict__ w3, const float* __restrict__ w4,
    float* __restrict__ V, float* __restrict__ acc)
{
    int t = blockIdx.x * blockDim.x + threadIdx.x;
    int j = t - 512;
    if (j >= 0 && j < 1360) acc[j] = 0.0f;   // zero banked BN accumulators
    if (t >= 340) return;
    const float* w; float* vout;
    if (t < 256)      { w = w1 + t*18;        vout = V + t*16; }
    else if (t < 320) { w = w2 + (t-256)*18;  vout = V + 4096 + (t-256)*16; }
    else if (t < 336) { w = w3 + (t-320)*18;  vout = V + 5120 + (t-320)*16; }
    else              { w = w4 + (t-336)*18;  vout = V + 5376 + (t-336)*16; }
    const int perm[8] = {0,5,7,2,3,6,4,1};   // CNOT ring row permutation
    float U[8][8];
    #pragma unroll
    for (int i=0;i<8;i++)
        #pragma unroll
        for (int jj=0;jj<8;jj++) U[i][jj] = (i==jj) ? 1.0f : 0.0f;
    for (int l=0;l<6;l++){
        float c0 = cosf(0.5f*w[l*3+0]), s0 = sinf(0.5f*w[l*3+0]);
        float c1 = cosf(0.5f*w[l*3+1]), s1 = sinf(0.5f*w[l*3+1]);
        float c2 = cosf(0.5f*w[l*3+2]), s2 = sinf(0.5f*w[l*3+2]);
        #pragma unroll
        for (int col=0; col<8; col++){
            float v[8];
            #pragma unroll
            for (int r=0;r<8;r++) v[r] = U[r][col];
            #pragma unroll
            for (int bb=0;bb<8;bb+=2){ float x=v[bb], y=v[bb+1]; v[bb]=c2*x-s2*y; v[bb+1]=s2*x+c2*y; }
            #pragma unroll
            for (int g=0;g<8;g+=4)
                #pragma unroll
                for (int i=0;i<2;i++){ int a=g+i, bq=g+i+2; float x=v[a], y=v[bq]; v[a]=c1*x-s1*y; v[bq]=s1*x+c1*y; }
            #pragma unroll
            for (int i=0;i<4;i++){ float x=v[i], y=v[i+4]; v[i]=c0*x-s0*y; v[i+4]=s0*x+c0*y; }
            #pragma unroll
            for (int r=0;r<8;r++) U[perm[r]][col] = v[r];
        }
    }
    #pragma unroll
    for (int jj=0;jj<4;jj++)
        #pragma unroll
        for (int k=0;k<4;k++) vout[jj*4+k] = U[jj][k];
}

// One thread = one (batch, channel, patch); NB blocks x 256 thr x 4 iters.
// BN of the INPUT (folded from accPrev) is applied on load; per-channel
// partial sums of the OUTPUT go to accOut (8-way banked global atomics).
template<int C, int H, int W, bool BN>
__global__ __launch_bounds__(256) void qcnn_kernel(
    const float* __restrict__ x, const float* __restrict__ V,
    const float* __restrict__ accPrev, const float* __restrict__ gamma,
    const float* __restrict__ beta, float invN,
    float* __restrict__ out, float* __restrict__ accOut)
{
    constexpr int HW  = H*W;
    constexpr int P   = HW/4;                 // patches per channel: 4,16,64,256
    constexpr int OW  = W/2;
    constexpr int LP  = (P==4)?2:(P==16)?4:(P==64)?6:8;
    constexpr int LOW = (OW==2)?1:(OW==4)?2:(OW==8)?3:4;
    constexpr int OC  = C/4;                  // BN channels of the OUTPUT
    constexpr int OCB = (64/P) < 1 ? 1 : (64/P);   // output-ch bins per block: 16,4,1,1
    constexpr int G   = (4*P < 64) ? 4*P : 64;     // lanes sharing one out-ch

    __shared__ float sBin[2*OCB];
    __shared__ float sSc[C], sSh[C];
    const int tid = threadIdx.x;

    if (tid < 2*OCB) sBin[tid] = 0.0f;
    if constexpr (BN){
        // fold banked accumulators of the previous layer into scale/shift
        if (tid < C){
            float s=0.0f, q=0.0f;
            #pragma unroll
            for (int bk=0;bk<8;bk++){
                s += accPrev[bk*2*C + tid];
                q += accPrev[bk*2*C + C + tid];
            }
            float mean = s*invN;
            float var  = q*invN - mean*mean;
            float r    = 1.0f / sqrtf(var + 1e-5f);
            float sc   = gamma[tid]*r;
            sSc[tid] = sc;
            sSh[tid] = beta[tid] - mean*sc;
        }
    }
    __syncthreads();

    const int r0  = (blockIdx.x & 3) * 256;   // per-batch flat r-range
    const int oc0 = r0 >> (LP+2);

    for (int it=0; it<4; ++it){
        int tg = (it<<18) + (blockIdx.x<<8) + tid;   // NB*256 = 2^18
        int b  = tg >> 10;
        int r  = tg & 1023;
        int c  = r >> LP;
        int p  = r & (P-1);
        int oh = p >> LOW;
        int ow = p & (OW-1);
        const float* xb = x + ((size_t)b<<12) + c*HW + (oh*2)*W + (ow*2);
        float2 t0 = *reinterpret_cast<const float2*>(xb);
        float2 t1 = *reinterpret_cast<const float2*>(xb + W);
        float x0=t0.x, x1=t0.y, x2=t1.x, x3=t1.y;
        if constexpr (BN){
            float sc = sSc[c], sh = sSh[c];
            x0 = fmaxf(fmaf(x0,sc,sh), 0.0f);
            x1 = fmaxf(fmaf(x1,sc,sh), 0.0f);
            x2 = fmaxf(fmaf(x2,sc,sh), 0.0f);
            x3 = fmaxf(fmaf(x3,sc,sh), 0.0f);
        }
        float nrm = sqrtf(x0*x0 + x1*x1 + x2*x2 + x3*x3);
        float inv = 1.0f / fmaxf(nrm, 1e-9f);
        float a0=x0*inv, a1=x1*inv, a2=x2*inv, a3=x3*inv;
        const float4* Vc = reinterpret_cast<const float4*>(V + (c<<4));
        float4 v0 = Vc[0], v1 = Vc[1], v2 = Vc[2], v3 = Vc[3];
        float q0 = v0.x*a0 + v0.y*a1 + v0.z*a2 + v0.w*a3;
        float q1 = v1.x*a0 + v1.y*a1 + v1.z*a2 + v1.w*a3;
        float q2 = v2.x*a0 + v2.y*a1 + v2.z*a2 + v2.w*a3;
        float q3 = v3.x*a0 + v3.y*a1 + v3.z*a2 + v3.w*a3;
        q0*=q0; q1*=q1; q2*=q2; q3*=q3;
        float dinv = 1.0f / fmaxf(q0+q1+q2+q3, 1e-9f);
        float d0=q0*dinv, d1=q1*dinv, d2=q2*dinv, d3=q3*dinv;
        *reinterpret_cast<float4*>(out + ((size_t)b<<12) + (r<<2)) =
            make_float4(d0,d1,d2,d3);
        float ls  = d0+d1+d2+d3;
        float lss = d0*d0 + d1*d1 + d2*d2 + d3*d3;
        #pragma unroll
        for (int off=1; off<G; off<<=1){
            ls  += __shfl_xor(ls,  off);
            lss += __shfl_xor(lss, off);
        }
        if ((tid & (G-1)) == 0){
            int ocl = (r >> (LP+2)) - oc0;
            atomicAdd(&sBin[ocl], ls);
            atomicAdd(&sBin[OCB + ocl], lss);
        }
    }
    __syncthreads();
    if (tid < OCB){
        int bank = blockIdx.x & 7;
        atomicAdd(&accOut[bank*2*OC + oc0 + tid],      sBin[tid]);
        atomicAdd(&accOut[bank*2*OC + OC + oc0 + tid], sBin[OCB + tid]);
    }
}

__global__ __launch_bounds__(256) void final_kernel(
    const float* __restrict__ s4, const float* __restrict__ acc4,
    const float* __restrict__ gf, const float* __restrict__ bf,
    float* __restrict__ out_tanh, float* __restrict__ out_bn)
{
    __shared__ float sP[2];
    if (threadIdx.x == 0){
        float s=0.0f, q=0.0f;
        #pragma unroll
        for (int bk=0;bk<8;bk++){ s += acc4[bk*2]; q += acc4[bk*2+1]; }
        float mean = s*(1.0f/4194304.0f);
        float var  = q*(1.0f/4194304.0f) - mean*mean;
        float r    = 1.0f / sqrtf(var + 1e-5f);
        float sc   = gf[0]*r;
        sP[0] = sc;
        sP[1] = bf[0] - mean*sc;
    }
    __syncthreads();
    float sc = sP[0], sh = sP[1];
    int i = blockIdx.x*blockDim.x + threadIdx.x;   // 1M float4s
    float4 v = reinterpret_cast<const float4*>(s4)[i];
    float4 bn = make_float4(fmaf(v.x,sc,sh), fmaf(v.y,sc,sh),
                            fmaf(v.z,sc,sh), fmaf(v.w,sc,sh));
    reinterpret_cast<float4*>(out_bn)[i] = bn;
    reinterpret_cast<float4*>(out_tanh)[i] =
        make_float4(tanhf(bn.x), tanhf(bn.y), tanhf(bn.z), tanhf(bn.w));
}

extern "C" void kernel_launch(void* const* d_in, const int* in_sizes, int n_in,
                              void* d_out, int out_size, void* d_ws, size_t ws_size,
                              hipStream_t stream)
{
    const float* z      = (const float*)d_in[0];
    const float* w1     = (const float*)d_in[1];
    const float* w2     = (const float*)d_in[2];
    const float* w3     = (const float*)d_in[3];
    const float* w4     = (const float*)d_in[4];
    const float* gamma2 = (const float*)d_in[5];
    const float* beta2  = (const float*)d_in[6];
    const float* gamma3 = (const float*)d_in[7];
    const float* beta3  = (const float*)d_in[8];
    const float* gamma4 = (const float*)d_in[9];
    const float* beta4  = (const float*)d_in[10];
    const float* gammaf = (const float*)d_in[11];
    const float* betaf  = (const float*)d_in[12];
    float* out = (float*)d_out;
    float* ws  = (float*)d_ws;

    float* V    = ws;          // 5440 floats
    float* acc  = ws + 8192;   // 1360 floats, 8-way banked:
    float* acc1 = acc;         //   8 * 128  (64 out-ch of L1)
    float* acc2 = acc + 1024;  //   8 * 32   (16 out-ch of L2)
    float* acc3 = acc + 1280;  //   8 * 8    ( 4 out-ch of L3)
    float* acc4 = acc + 1344;  //   8 * 2    ( 1 out-ch of L4)
    float* bufA = ws + 16384;               // 4M floats (s1, then s3)
    float* bufB = ws + 16384 + 4194304;     // 4M floats (s2)

    float* out_tanh = out;                  // output 0
    float* s4       = out + 4194304;        // output 1 (written by L4)
    float* out_bn   = out + 8388608;        // output 2

    build_V_kernel<<<8, 256, 0, stream>>>(w1, w2, w3, w4, V, acc);

    qcnn_kernel<256,4,4,false><<<NB, 256, 0, stream>>>(
        z, V, nullptr, nullptr, nullptr, 0.0f, bufA, acc1);
    qcnn_kernel<64,8,8,true><<<NB, 256, 0, stream>>>(
        bufA, V+4096, acc1, gamma2, beta2, 1.0f/65536.0f, bufB, acc2);
    qcnn_kernel<16,16,16,true><<<NB, 256, 0, stream>>>(
        bufB, V+5120, acc2, gamma3, beta3, 1.0f/262144.0f, bufA, acc3);
    qcnn_kernel<4,32,32,true><<<NB, 256, 0, stream>>>(
        bufA, V+5376, acc3, gamma4, beta4, 1.0f/1048576.0f, s4, acc4);
    final_kernel<<<4096, 256, 0, stream>>>(
        s4, acc4, gammaf, betaf, out_tanh, out_bn);
}